// Round 1
// baseline (4411.898 us; speedup 1.0000x reference)
//
#include <hip/hip_runtime.h>

typedef unsigned short ushort_t;
typedef unsigned int uint_t;
typedef __attribute__((ext_vector_type(8))) short short8;
typedef __attribute__((ext_vector_type(4))) float f32x4;

#define Tn 256
#define Bn 64
#define Hn 512
#define En 256
#define G4 2048
#define Nt 6

// ---------- helpers ----------
__device__ inline ushort_t f2bf(float f) {
    uint_t u = __float_as_uint(f);
    uint_t r = u + 0x7FFFu + ((u >> 16) & 1u);
    return (ushort_t)(r >> 16);
}
__device__ inline float bf2f(ushort_t h) { return __uint_as_float(((uint_t)h) << 16); }
__device__ inline float sigm(float x) { return 1.f / (1.f + __expf(-x)); }
__device__ inline float tanh_(float x) { return 2.f / (1.f + __expf(-2.f * x)) - 1.f; }

// ---------- ws layout (bytes) ----------
#define OFF_XBF    0u               // 16384*256 bf16        = 8,388,608
#define OFF_WIH    8388608u         // 2*2048*256 bf16       = 2,097,152
#define OFF_WHH    10485760u        // 2*2048*512 bf16       = 4,194,304
#define OFF_HGLOB  14680064u        // 2*2*64*512 bf16       = 262,144
#define OFF_HS     14942208u        // 16384*1024 bf16       = 33,554,432
#define OFF_EMIS   48496640u        // 16384*6 f32           = 393,216
#define OFF_BAR    48889856u        // barrier ints

// ---------- kernel 1: prep ----------
__global__ void prep_kernel(const int* __restrict__ sent, const float* __restrict__ embed,
                            const float* __restrict__ Wihf, const float* __restrict__ Whhf,
                            const float* __restrict__ Wihb, const float* __restrict__ Whhb,
                            const float* __restrict__ h0, float* __restrict__ out,
                            ushort_t* __restrict__ x_bf, ushort_t* __restrict__ Wih_bf,
                            ushort_t* __restrict__ Whh_bf, ushort_t* __restrict__ hglob,
                            int* __restrict__ bar) {
    long i = (long)blockIdx.x * 256 + threadIdx.x;
    const long n0 = 2097152, n1 = 1048576, n2 = 4194304, n3 = 65536;
    if (i < n0) {  // Whh cast: [dir][2048][512]
        long d = i >> 20, r = i & 1048575;
        const float* W = d ? Whhb : Whhf;
        Whh_bf[i] = f2bf(W[r]);
        return;
    }
    i -= n0;
    if (i < n1) {  // Wih cast: [dir][2048][256]
        long d = i >> 19, r = i & 524287;
        const float* W = d ? Wihb : Wihf;
        Wih_bf[(d << 19) + r] = f2bf(W[r]);
        return;
    }
    i -= n1;
    if (i < n2) {  // x gather: row = t*B+b
        long row = i >> 8, e = i & 255;
        int tok = sent[row];
        x_bf[i] = f2bf(embed[(size_t)tok * 256 + e]);
        return;
    }
    i -= n2;
    if (i < n3) {  // h0 -> hglob[dir][buf0][b][k]
        long dir = i >> 15, rem = i & 32767;
        hglob[dir * 65536 + rem] = f2bf(h0[i]);
        return;
    }
    i -= n3;
    if (i < 1024) { bar[i] = 0; return; }
    if (i == 1024) { out[0] = 0.f; }
}

// ---------- kernel 2: persistent fused BiLSTM ----------
// 128 WGs: dir(2) x batch-half(2) x gate-slice(32).  256 threads.
__global__ void __launch_bounds__(256, 1) lstm_kernel(
    const ushort_t* __restrict__ x_bf, const ushort_t* __restrict__ Wih_bf,
    const ushort_t* __restrict__ Whh_bf, const float* __restrict__ biasf,
    const float* __restrict__ biasb, const float* __restrict__ c0,
    const int* __restrict__ mask, ushort_t* __restrict__ hglob,
    ushort_t* __restrict__ hs, int* __restrict__ bar) {

    __shared__ __align__(16) ushort_t x_s[32 * 264];
    __shared__ __align__(16) ushort_t h_s[32 * 520];
    __shared__ __align__(16) float gates_s[64 * 33];

    const int tid = threadIdx.x;
    const int wid = blockIdx.x;
    const int dir = wid >> 6;
    const int bh  = (wid >> 5) & 1;
    const int gs  = wid & 31;
    const int j0  = gs * 16;
    const int group = dir * 2 + bh;
    int* cnt = &bar[group * 128];
    int* gen = &bar[group * 128 + 64];

    const int lane = tid & 63;
    const int wv = tid >> 6;            // wave = gate type (i,f,g,o)
    const int qo = (lane >> 4) * 8;     // k-chunk offset in fragment
    const int ml = lane & 15;

    // persistent B fragments (W_ih: 8 ksteps, W_hh: 16 ksteps) in VGPRs
    const int grow = wv * 512 + j0 + ml;   // global gate row 0..2047
    short8 bxf[8], bhf[16];
    {
        const ushort_t* wr = Wih_bf + (size_t)dir * G4 * En + (size_t)grow * En + qo;
        #pragma unroll
        for (int ks = 0; ks < 8; ++ks) bxf[ks] = *(const short8*)(wr + ks * 32);
        const ushort_t* wr2 = Whh_bf + (size_t)dir * G4 * Hn + (size_t)grow * Hn + qo;
        #pragma unroll
        for (int ks = 0; ks < 16; ++ks) bhf[ks] = *(const short8*)(wr2 + ks * 32);
    }
    const float bv = (dir ? biasb : biasf)[grow];

    // update-phase mapping & persistent cell state (2 cells/thread)
    const int jl = tid >> 4;            // 0..15  (h column within slice)
    const int bl0 = (tid & 15) * 2;     // local batch base
    float creg[2];
    #pragma unroll
    for (int r = 0; r < 2; ++r) {
        int bg = bh * 32 + bl0 + r;
        creg[r] = c0[(size_t)dir * Bn * Hn + (size_t)bg * Hn + j0 + jl];
    }

    const ushort_t* xbase = x_bf + (size_t)bh * 32 * En;
    ushort_t* hgbase = hglob + (size_t)dir * 2 * Bn * Hn + (size_t)bh * 32 * Hn;

    for (int s = 0; s < Tn; ++s) {
        const int t = dir ? (Tn - 1 - s) : s;
        const int cur = s & 1, nxt = cur ^ 1;

        {   // stage x[t] slice (16KB) and h_cur slice (32KB) into LDS
            const uint4* g4 = (const uint4*)(xbase + (size_t)t * Bn * En);
            #pragma unroll
            for (int k = 0; k < 4; ++k) {
                int c16 = tid + k * 256;
                int row = c16 >> 5, col = c16 & 31;
                *(uint4*)&x_s[row * 264 + col * 8] = g4[c16];
            }
            const uint4* h4 = (const uint4*)(hgbase + (size_t)cur * Bn * Hn);
            #pragma unroll
            for (int k = 0; k < 8; ++k) {
                int c16 = tid + k * 256;
                int row = c16 >> 6, col = c16 & 63;
                *(uint4*)&h_s[row * 520 + col * 8] = h4[c16];
            }
        }
        __syncthreads();

        // gates = bias + x@Wih^T + h@Whh^T   (M=32 batches, N=16 gates/wave)
        f32x4 acc0, acc1;
        #pragma unroll
        for (int r = 0; r < 4; ++r) { acc0[r] = bv; acc1[r] = bv; }
        {
            const ushort_t* xr0 = &x_s[ml * 264 + qo];
            const ushort_t* xr1 = &x_s[(16 + ml) * 264 + qo];
            #pragma unroll
            for (int ks = 0; ks < 8; ++ks) {
                short8 a0 = *(const short8*)(xr0 + ks * 32);
                short8 a1 = *(const short8*)(xr1 + ks * 32);
                acc0 = __builtin_amdgcn_mfma_f32_16x16x32_bf16(a0, bxf[ks], acc0, 0, 0, 0);
                acc1 = __builtin_amdgcn_mfma_f32_16x16x32_bf16(a1, bxf[ks], acc1, 0, 0, 0);
            }
            const ushort_t* hr0 = &h_s[ml * 520 + qo];
            const ushort_t* hr1 = &h_s[(16 + ml) * 520 + qo];
            #pragma unroll
            for (int ks = 0; ks < 16; ++ks) {
                short8 a0 = *(const short8*)(hr0 + ks * 32);
                short8 a1 = *(const short8*)(hr1 + ks * 32);
                acc0 = __builtin_amdgcn_mfma_f32_16x16x32_bf16(a0, bhf[ks], acc0, 0, 0, 0);
                acc1 = __builtin_amdgcn_mfma_f32_16x16x32_bf16(a1, bhf[ks], acc1, 0, 0, 0);
            }
        }
        {   // C layout: col=lane&15 (gate), row=(lane>>4)*4+reg (batch)
            int nl = wv * 16 + ml;
            int br = (lane >> 4) * 4;
            #pragma unroll
            for (int r = 0; r < 4; ++r) {
                gates_s[nl * 33 + br + r]      = acc0[r];
                gates_s[nl * 33 + 16 + br + r] = acc1[r];
            }
        }
        __syncthreads();

        // cell update: thread -> (jl, bl0..bl0+1)
        {
            #pragma unroll
            for (int r = 0; r < 2; ++r) {
                int bl = bl0 + r;
                int bg = bh * 32 + bl;
                float iv = gates_s[jl * 33 + bl];
                float fv = gates_s[(16 + jl) * 33 + bl];
                float gv = gates_s[(32 + jl) * 33 + bl];
                float ov = gates_s[(48 + jl) * 33 + bl];
                float cn = sigm(fv) * creg[r] + sigm(iv) * tanh_(gv);
                float hn = sigm(ov) * tanh_(cn);
                int mv = mask[t * Bn + bg];
                float hp = bf2f(h_s[bl * 520 + j0 + jl]);
                float h2, hsv;
                if (mv) { creg[r] = cn; h2 = hn; hsv = hn; }
                else    { h2 = hp; hsv = 0.f; }
                hgbase[(size_t)nxt * Bn * Hn + (size_t)bl * Hn + j0 + jl] = f2bf(h2);
                hs[((size_t)t * Bn + bg) * 1024 + dir * 512 + j0 + jl] = f2bf(hsv);
            }
        }

        // inter-WG barrier within group of 32 (sense via generation counter)
        __syncthreads();
        if (tid == 0) {
            __threadfence();
            int g0 = __hip_atomic_load(gen, __ATOMIC_RELAXED, __HIP_MEMORY_SCOPE_AGENT);
            int prev = __hip_atomic_fetch_add(cnt, 1, __ATOMIC_ACQ_REL, __HIP_MEMORY_SCOPE_AGENT);
            if (prev == 31) {
                __hip_atomic_store(cnt, 0, __ATOMIC_RELAXED, __HIP_MEMORY_SCOPE_AGENT);
                __hip_atomic_fetch_add(gen, 1, __ATOMIC_RELEASE, __HIP_MEMORY_SCOPE_AGENT);
            } else {
                while (__hip_atomic_load(gen, __ATOMIC_ACQUIRE, __HIP_MEMORY_SCOPE_AGENT) == g0)
                    __builtin_amdgcn_s_sleep(1);
            }
            __threadfence();
        }
        __syncthreads();
    }
}

// ---------- kernel 3: emission projection (wave per row) ----------
__global__ void emis_kernel(const ushort_t* __restrict__ hs, const float* __restrict__ Wout,
                            const float* __restrict__ bout, float* __restrict__ emis) {
    int row = blockIdx.x * 4 + (threadIdx.x >> 6);
    int lane = threadIdx.x & 63;
    const ushort_t* hr = hs + (size_t)row * 1024;
    float acc[6] = {0, 0, 0, 0, 0, 0};
    for (int kk = 0; kk < 16; ++kk) {
        int k = kk * 64 + lane;
        float h = bf2f(hr[k]);
        #pragma unroll
        for (int n = 0; n < Nt; ++n) acc[n] += h * Wout[n * 1024 + k];
    }
    #pragma unroll
    for (int n = 0; n < Nt; ++n) {
        float v = acc[n];
        #pragma unroll
        for (int off = 32; off; off >>= 1) v += __shfl_down(v, off);
        if (lane == 0) emis[row * Nt + n] = v + bout[n];
    }
}

// ---------- kernel 4: CRF LLH (one wave per batch) ----------
__global__ void crf_kernel(const int* __restrict__ tags, const int* __restrict__ mask,
                           const float* __restrict__ emis, const float* __restrict__ trans,
                           const float* __restrict__ startt, const float* __restrict__ endt,
                           float* __restrict__ out) {
    int b = blockIdx.x;
    int lane = threadIdx.x;

    // numerator partials over strided t
    float part = 0.f;
    int mc = 0;
    for (int t = lane; t < Tn; t += 64) {
        int mv = mask[t * Bn + b];
        mc += mv;
        if (t >= 1) {
            int tp = tags[(t - 1) * Bn + b], tc = tags[t * Bn + b];
            part += (trans[tp * Nt + tc] + emis[(t * Bn + b) * Nt + tc]) * (float)mv;
        }
    }
    #pragma unroll
    for (int off = 32; off; off >>= 1) {
        part += __shfl_down(part, off);
        mc += __shfl_down(mc, off);
    }
    float num = 0.f;
    if (lane == 0) {
        int t0g = tags[b];
        num = startt[t0g] + emis[b * Nt + t0g] + part;
        int last = mc - 1;
        num += endt[tags[last * Bn + b]];
    }

    // denominator: forward algorithm, lanes 0..5 hold score[j]
    if (lane < Nt) {
        int j = lane;
        float tr[6];
        #pragma unroll
        for (int i = 0; i < Nt; ++i) tr[i] = trans[i * Nt + j];
        float score = startt[j] + emis[b * Nt + j];
        for (int t = 1; t < Tn; ++t) {
            float e = emis[(t * Bn + b) * Nt + j];
            int mv = mask[t * Bn + b];
            float v[6];
            float mx = -1e30f;
            #pragma unroll
            for (int i = 0; i < Nt; ++i) { v[i] = __shfl(score, i) + tr[i]; mx = fmaxf(mx, v[i]); }
            float sm = 0.f;
            #pragma unroll
            for (int i = 0; i < Nt; ++i) sm += __expf(v[i] - mx);
            float nxtv = mx + __logf(sm) + e;
            score = mv > 0 ? nxtv : score;
        }
        float fvv = score + endt[j];
        float m2 = fvv;
        #pragma unroll
        for (int i = 0; i < Nt; ++i) m2 = fmaxf(m2, __shfl(fvv, i));
        float s2 = 0.f;
        #pragma unroll
        for (int i = 0; i < Nt; ++i) s2 += __expf(__shfl(fvv, i) - m2);
        if (lane == 0) {
            float denom = m2 + __logf(s2);
            atomicAdd(out, num - denom);
        }
    }
}

extern "C" void kernel_launch(void* const* d_in, const int* in_sizes, int n_in,
                              void* d_out, int out_size, void* d_ws, size_t ws_size,
                              hipStream_t stream) {
    (void)in_sizes; (void)n_in; (void)out_size; (void)ws_size;
    const int*   sent  = (const int*)d_in[0];
    const int*   tags  = (const int*)d_in[1];
    const int*   mask  = (const int*)d_in[2];
    const float* h0    = (const float*)d_in[3];
    const float* c0    = (const float*)d_in[4];
    const float* embed = (const float*)d_in[5];
    const float* Wihf  = (const float*)d_in[6];
    const float* Whhf  = (const float*)d_in[7];
    const float* bf_   = (const float*)d_in[8];
    const float* Wihb  = (const float*)d_in[9];
    const float* Whhb  = (const float*)d_in[10];
    const float* bb_   = (const float*)d_in[11];
    const float* Wout  = (const float*)d_in[12];
    const float* bout  = (const float*)d_in[13];
    const float* trans = (const float*)d_in[14];
    const float* stt   = (const float*)d_in[15];
    const float* ent   = (const float*)d_in[16];
    float* out = (float*)d_out;
    char* ws = (char*)d_ws;

    ushort_t* x_bf   = (ushort_t*)(ws + OFF_XBF);
    ushort_t* Wih_bf = (ushort_t*)(ws + OFF_WIH);
    ushort_t* Whh_bf = (ushort_t*)(ws + OFF_WHH);
    ushort_t* hglob  = (ushort_t*)(ws + OFF_HGLOB);
    ushort_t* hs     = (ushort_t*)(ws + OFF_HS);
    float*    emis   = (float*)(ws + OFF_EMIS);
    int*      bar    = (int*)(ws + OFF_BAR);

    prep_kernel<<<28933, 256, 0, stream>>>(sent, embed, Wihf, Whhf, Wihb, Whhb,
                                           h0, out, x_bf, Wih_bf, Whh_bf, hglob, bar);
    lstm_kernel<<<128, 256, 0, stream>>>(x_bf, Wih_bf, Whh_bf, bf_, bb_, c0,
                                         mask, hglob, hs, bar);
    emis_kernel<<<4096, 256, 0, stream>>>(hs, Wout, bout, emis);
    crf_kernel<<<64, 64, 0, stream>>>(tags, mask, emis, trans, stt, ent, out);
}

// Round 2
// 2019.990 us; speedup vs baseline: 2.1841x; 2.1841x over previous
//
#include <hip/hip_runtime.h>

typedef unsigned short ushort_t;
typedef unsigned int uint_t;
typedef __attribute__((ext_vector_type(8))) short short8;
typedef __attribute__((ext_vector_type(4))) float f32x4;

#define Tn 256
#define Bn 64
#define Hn 512
#define En 256
#define G4 2048
#define Nt 6

// ---------- helpers ----------
__device__ inline ushort_t f2bf(float f) {
    uint_t u = __float_as_uint(f);
    uint_t r = u + 0x7FFFu + ((u >> 16) & 1u);
    return (ushort_t)(r >> 16);
}
__device__ inline float bf2f(ushort_t h) { return __uint_as_float(((uint_t)h) << 16); }
__device__ inline float sigm(float x) { return 1.f / (1.f + __expf(-x)); }
__device__ inline float tanh_(float x) { return 2.f / (1.f + __expf(-2.f * x)) - 1.f; }

// ---------- ws layout (bytes) ----------
#define OFF_XBF    0u               // 16384*256 bf16        = 8,388,608
#define OFF_WIH    8388608u         // 2*2048*256 bf16       = 2,097,152
#define OFF_WHH    10485760u        // 2*2048*512 bf16       = 4,194,304
#define OFF_HGLOB  14680064u        // 2*2*64*512 bf16       = 262,144
#define OFF_HS     14942208u        // 16384*1024 bf16       = 33,554,432
#define OFF_EMIS   48496640u        // 16384*6 f32           = 393,216
#define OFF_BAR    48889856u        // 4 groups * 1024 ints  = 16,384

// ---------- kernel 1: prep ----------
__global__ void prep_kernel(const int* __restrict__ sent, const float* __restrict__ embed,
                            const float* __restrict__ Wihf, const float* __restrict__ Whhf,
                            const float* __restrict__ Wihb, const float* __restrict__ Whhb,
                            const float* __restrict__ h0, float* __restrict__ out,
                            ushort_t* __restrict__ x_bf, ushort_t* __restrict__ Wih_bf,
                            ushort_t* __restrict__ Whh_bf, ushort_t* __restrict__ hglob,
                            int* __restrict__ bar) {
    long i = (long)blockIdx.x * 256 + threadIdx.x;
    const long n0 = 2097152, n1 = 1048576, n2 = 4194304, n3 = 65536;
    if (i < n0) {  // Whh cast: [dir][2048][512]
        long d = i >> 20, r = i & 1048575;
        const float* W = d ? Whhb : Whhf;
        Whh_bf[i] = f2bf(W[r]);
        return;
    }
    i -= n0;
    if (i < n1) {  // Wih cast: [dir][2048][256]
        long d = i >> 19, r = i & 524287;
        const float* W = d ? Wihb : Wihf;
        Wih_bf[(d << 19) + r] = f2bf(W[r]);
        return;
    }
    i -= n1;
    if (i < n2) {  // x gather: row = t*B+b
        long row = i >> 8, e = i & 255;
        int tok = sent[row];
        x_bf[i] = f2bf(embed[(size_t)tok * 256 + e]);
        return;
    }
    i -= n2;
    if (i < n3) {  // h0 -> hglob[dir][buf0][b][k]
        long dir = i >> 15, rem = i & 32767;
        hglob[dir * 65536 + rem] = f2bf(h0[i]);
        return;
    }
    i -= n3;
    if (i < 4096) { bar[i] = 0; return; }
    if (i == 4096) { out[0] = 0.f; }
}

// ---------- kernel 2: persistent fused BiLSTM ----------
// 128 WGs: dir(2) x batch-half(2) x gate-slice(32).  256 threads.
__global__ void __launch_bounds__(256, 1) lstm_kernel(
    const ushort_t* __restrict__ x_bf, const ushort_t* __restrict__ Wih_bf,
    const ushort_t* __restrict__ Whh_bf, const float* __restrict__ biasf,
    const float* __restrict__ biasb, const float* __restrict__ c0,
    const int* __restrict__ mask, ushort_t* __restrict__ hglob,
    ushort_t* __restrict__ hs, int* __restrict__ bar) {

    __shared__ __align__(16) ushort_t x_s[32 * 264];
    __shared__ __align__(16) ushort_t h_s[32 * 520];
    __shared__ __align__(16) float gates_s[64 * 33];

    const int tid = threadIdx.x;
    const int wid = blockIdx.x;
    const int dir = wid >> 6;
    const int bh  = (wid >> 5) & 1;
    const int gs  = wid & 31;
    const int j0  = gs * 16;
    const int group = dir * 2 + bh;
    int* flags = &bar[group * 1024];   // 32 peers, 32-int (128B) stride each

    const int lane = tid & 63;
    const int wv = tid >> 6;            // wave = gate type (i,f,g,o)
    const int qo = (lane >> 4) * 8;     // k-chunk offset in fragment
    const int ml = lane & 15;

    // persistent B fragments (W_ih: 8 ksteps, W_hh: 16 ksteps) in VGPRs
    const int grow = wv * 512 + j0 + ml;   // global gate row 0..2047
    short8 bxf[8], bhf[16];
    {
        const ushort_t* wr = Wih_bf + (size_t)dir * G4 * En + (size_t)grow * En + qo;
        #pragma unroll
        for (int ks = 0; ks < 8; ++ks) bxf[ks] = *(const short8*)(wr + ks * 32);
        const ushort_t* wr2 = Whh_bf + (size_t)dir * G4 * Hn + (size_t)grow * Hn + qo;
        #pragma unroll
        for (int ks = 0; ks < 16; ++ks) bhf[ks] = *(const short8*)(wr2 + ks * 32);
    }
    const float bv = (dir ? biasb : biasf)[grow];

    // update-phase mapping & persistent cell state (2 cells/thread)
    const int jl = tid >> 4;            // 0..15  (h column within slice)
    const int bl0 = (tid & 15) * 2;     // local batch base
    float creg[2];
    #pragma unroll
    for (int r = 0; r < 2; ++r) {
        int bg = bh * 32 + bl0 + r;
        creg[r] = c0[(size_t)dir * Bn * Hn + (size_t)bg * Hn + j0 + jl];
    }

    const ushort_t* xbase = x_bf + (size_t)bh * 32 * En;
    ushort_t* hgbase = hglob + (size_t)dir * 2 * Bn * Hn + (size_t)bh * 32 * Hn;

    for (int s = 0; s < Tn; ++s) {
        const int t = dir ? (Tn - 1 - s) : s;
        const int cur = s & 1, nxt = cur ^ 1;

        {   // stage x[t] slice (16KB) and h_cur slice (32KB) into LDS
            const uint4* g4 = (const uint4*)(xbase + (size_t)t * Bn * En);
            #pragma unroll
            for (int k = 0; k < 4; ++k) {
                int c16 = tid + k * 256;
                int row = c16 >> 5, col = c16 & 31;
                *(uint4*)&x_s[row * 264 + col * 8] = g4[c16];
            }
            const uint4* h4 = (const uint4*)(hgbase + (size_t)cur * Bn * Hn);
            #pragma unroll
            for (int k = 0; k < 8; ++k) {
                int c16 = tid + k * 256;
                int row = c16 >> 6, col = c16 & 63;
                *(uint4*)&h_s[row * 520 + col * 8] = h4[c16];
            }
        }
        __syncthreads();

        // gates = bias + x@Wih^T + h@Whh^T   (M=32 batches, N=16 gates/wave)
        f32x4 acc0, acc1;
        #pragma unroll
        for (int r = 0; r < 4; ++r) { acc0[r] = bv; acc1[r] = bv; }
        {
            const ushort_t* xr0 = &x_s[ml * 264 + qo];
            const ushort_t* xr1 = &x_s[(16 + ml) * 264 + qo];
            #pragma unroll
            for (int ks = 0; ks < 8; ++ks) {
                short8 a0 = *(const short8*)(xr0 + ks * 32);
                short8 a1 = *(const short8*)(xr1 + ks * 32);
                acc0 = __builtin_amdgcn_mfma_f32_16x16x32_bf16(a0, bxf[ks], acc0, 0, 0, 0);
                acc1 = __builtin_amdgcn_mfma_f32_16x16x32_bf16(a1, bxf[ks], acc1, 0, 0, 0);
            }
            const ushort_t* hr0 = &h_s[ml * 520 + qo];
            const ushort_t* hr1 = &h_s[(16 + ml) * 520 + qo];
            #pragma unroll
            for (int ks = 0; ks < 16; ++ks) {
                short8 a0 = *(const short8*)(hr0 + ks * 32);
                short8 a1 = *(const short8*)(hr1 + ks * 32);
                acc0 = __builtin_amdgcn_mfma_f32_16x16x32_bf16(a0, bhf[ks], acc0, 0, 0, 0);
                acc1 = __builtin_amdgcn_mfma_f32_16x16x32_bf16(a1, bhf[ks], acc1, 0, 0, 0);
            }
        }
        {   // C layout: col=lane&15 (gate), row=(lane>>4)*4+reg (batch)
            int nl = wv * 16 + ml;
            int br = (lane >> 4) * 4;
            #pragma unroll
            for (int r = 0; r < 4; ++r) {
                gates_s[nl * 33 + br + r]      = acc0[r];
                gates_s[nl * 33 + 16 + br + r] = acc1[r];
            }
        }
        __syncthreads();

        // cell update: thread -> (jl, bl0..bl0+1)
        {
            #pragma unroll
            for (int r = 0; r < 2; ++r) {
                int bl = bl0 + r;
                int bg = bh * 32 + bl;
                float iv = gates_s[jl * 33 + bl];
                float fv = gates_s[(16 + jl) * 33 + bl];
                float gv = gates_s[(32 + jl) * 33 + bl];
                float ov = gates_s[(48 + jl) * 33 + bl];
                float cn = sigm(fv) * creg[r] + sigm(iv) * tanh_(gv);
                float hn = sigm(ov) * tanh_(cn);
                int mv = mask[t * Bn + bg];
                float hp = bf2f(h_s[bl * 520 + j0 + jl]);
                float h2, hsv;
                if (mv) { creg[r] = cn; h2 = hn; hsv = hn; }
                else    { h2 = hp; hsv = 0.f; }
                hgbase[(size_t)nxt * Bn * Hn + (size_t)bl * Hn + j0 + jl] = f2bf(h2);
                hs[((size_t)t * Bn + bg) * 1024 + dir * 512 + j0 + jl] = f2bf(hsv);
            }
        }

        // distributed epoch-flag barrier across the 32 WGs of this group.
        // __syncthreads() drains every wave's vmcnt (stores committed to L2);
        // lane 0's RELEASE fence (one buffer_wbl2) publishes the whole L2 to
        // the coherence point; peers poll RELAXED (no per-poll cache op),
        // then ONE ACQUIRE fence (one buffer_inv) before the next h stage.
        __syncthreads();
        if (tid < 32) {
            if (tid == 0) {
                __builtin_amdgcn_fence(__ATOMIC_RELEASE, "agent");
                __hip_atomic_store(&flags[gs * 32], s + 1, __ATOMIC_RELAXED,
                                   __HIP_MEMORY_SCOPE_AGENT);
            }
            int* pf = &flags[tid * 32];
            while (__hip_atomic_load(pf, __ATOMIC_RELAXED, __HIP_MEMORY_SCOPE_AGENT) < s + 1)
                __builtin_amdgcn_s_sleep(2);
            __builtin_amdgcn_fence(__ATOMIC_ACQUIRE, "agent");
        }
        __syncthreads();
    }
}

// ---------- kernel 3: emission projection (wave per row) ----------
__global__ void emis_kernel(const ushort_t* __restrict__ hs, const float* __restrict__ Wout,
                            const float* __restrict__ bout, float* __restrict__ emis) {
    int row = blockIdx.x * 4 + (threadIdx.x >> 6);
    int lane = threadIdx.x & 63;
    const ushort_t* hr = hs + (size_t)row * 1024;
    float acc[6] = {0, 0, 0, 0, 0, 0};
    for (int kk = 0; kk < 16; ++kk) {
        int k = kk * 64 + lane;
        float h = bf2f(hr[k]);
        #pragma unroll
        for (int n = 0; n < Nt; ++n) acc[n] += h * Wout[n * 1024 + k];
    }
    #pragma unroll
    for (int n = 0; n < Nt; ++n) {
        float v = acc[n];
        #pragma unroll
        for (int off = 32; off; off >>= 1) v += __shfl_down(v, off);
        if (lane == 0) emis[row * Nt + n] = v + bout[n];
    }
}

// ---------- kernel 4: CRF LLH (one wave per batch) ----------
__global__ void crf_kernel(const int* __restrict__ tags, const int* __restrict__ mask,
                           const float* __restrict__ emis, const float* __restrict__ trans,
                           const float* __restrict__ startt, const float* __restrict__ endt,
                           float* __restrict__ out) {
    int b = blockIdx.x;
    int lane = threadIdx.x;

    // numerator partials over strided t
    float part = 0.f;
    int mc = 0;
    for (int t = lane; t < Tn; t += 64) {
        int mv = mask[t * Bn + b];
        mc += mv;
        if (t >= 1) {
            int tp = tags[(t - 1) * Bn + b], tc = tags[t * Bn + b];
            part += (trans[tp * Nt + tc] + emis[(t * Bn + b) * Nt + tc]) * (float)mv;
        }
    }
    #pragma unroll
    for (int off = 32; off; off >>= 1) {
        part += __shfl_down(part, off);
        mc += __shfl_down(mc, off);
    }
    float num = 0.f;
    if (lane == 0) {
        int t0g = tags[b];
        num = startt[t0g] + emis[b * Nt + t0g] + part;
        int last = mc - 1;
        num += endt[tags[last * Bn + b]];
    }

    // denominator: forward algorithm, lanes 0..5 hold score[j]
    if (lane < Nt) {
        int j = lane;
        float tr[6];
        #pragma unroll
        for (int i = 0; i < Nt; ++i) tr[i] = trans[i * Nt + j];
        float score = startt[j] + emis[b * Nt + j];
        for (int t = 1; t < Tn; ++t) {
            float e = emis[(t * Bn + b) * Nt + j];
            int mv = mask[t * Bn + b];
            float v[6];
            float mx = -1e30f;
            #pragma unroll
            for (int i = 0; i < Nt; ++i) { v[i] = __shfl(score, i) + tr[i]; mx = fmaxf(mx, v[i]); }
            float sm = 0.f;
            #pragma unroll
            for (int i = 0; i < Nt; ++i) sm += __expf(v[i] - mx);
            float nxtv = mx + __logf(sm) + e;
            score = mv > 0 ? nxtv : score;
        }
        float fvv = score + endt[j];
        float m2 = fvv;
        #pragma unroll
        for (int i = 0; i < Nt; ++i) m2 = fmaxf(m2, __shfl(fvv, i));
        float s2 = 0.f;
        #pragma unroll
        for (int i = 0; i < Nt; ++i) s2 += __expf(__shfl(fvv, i) - m2);
        if (lane == 0) {
            float denom = m2 + __logf(s2);
            atomicAdd(out, num - denom);
        }
    }
}

extern "C" void kernel_launch(void* const* d_in, const int* in_sizes, int n_in,
                              void* d_out, int out_size, void* d_ws, size_t ws_size,
                              hipStream_t stream) {
    (void)in_sizes; (void)n_in; (void)out_size; (void)ws_size;
    const int*   sent  = (const int*)d_in[0];
    const int*   tags  = (const int*)d_in[1];
    const int*   mask  = (const int*)d_in[2];
    const float* h0    = (const float*)d_in[3];
    const float* c0    = (const float*)d_in[4];
    const float* embed = (const float*)d_in[5];
    const float* Wihf  = (const float*)d_in[6];
    const float* Whhf  = (const float*)d_in[7];
    const float* bf_   = (const float*)d_in[8];
    const float* Wihb  = (const float*)d_in[9];
    const float* Whhb  = (const float*)d_in[10];
    const float* bb_   = (const float*)d_in[11];
    const float* Wout  = (const float*)d_in[12];
    const float* bout  = (const float*)d_in[13];
    const float* trans = (const float*)d_in[14];
    const float* stt   = (const float*)d_in[15];
    const float* ent   = (const float*)d_in[16];
    float* out = (float*)d_out;
    char* ws = (char*)d_ws;

    ushort_t* x_bf   = (ushort_t*)(ws + OFF_XBF);
    ushort_t* Wih_bf = (ushort_t*)(ws + OFF_WIH);
    ushort_t* Whh_bf = (ushort_t*)(ws + OFF_WHH);
    ushort_t* hglob  = (ushort_t*)(ws + OFF_HGLOB);
    ushort_t* hs     = (ushort_t*)(ws + OFF_HS);
    float*    emis   = (float*)(ws + OFF_EMIS);
    int*      bar    = (int*)(ws + OFF_BAR);

    prep_kernel<<<28945, 256, 0, stream>>>(sent, embed, Wihf, Whhf, Wihb, Whhb,
                                           h0, out, x_bf, Wih_bf, Whh_bf, hglob, bar);
    lstm_kernel<<<128, 256, 0, stream>>>(x_bf, Wih_bf, Whh_bf, bf_, bb_, c0,
                                         mask, hglob, hs, bar);
    emis_kernel<<<4096, 256, 0, stream>>>(hs, Wout, bout, emis);
    crf_kernel<<<64, 64, 0, stream>>>(tags, mask, emis, trans, stt, ent, out);
}

// Round 3
// 1735.129 us; speedup vs baseline: 2.5427x; 1.1642x over previous
//
#include <hip/hip_runtime.h>

typedef unsigned short ushort_t;
typedef unsigned int uint_t;
typedef __attribute__((ext_vector_type(8))) short short8;
typedef __attribute__((ext_vector_type(4))) float f32x4;

#define Tn 256
#define Bn 64
#define Hn 512
#define En 256
#define G4 2048
#define Nt 6

// ---------- helpers ----------
__device__ inline ushort_t f2bf(float f) {
    uint_t u = __float_as_uint(f);
    uint_t r = u + 0x7FFFu + ((u >> 16) & 1u);
    return (ushort_t)(r >> 16);
}
__device__ inline float bf2f(ushort_t h) { return __uint_as_float(((uint_t)h) << 16); }
__device__ inline float sigm(float x) { return 1.f / (1.f + __expf(-x)); }
__device__ inline float tanh_(float x) { return 2.f / (1.f + __expf(-2.f * x)) - 1.f; }

// ---------- ws layout (bytes) ----------
#define OFF_XBF    0u               // 16384*256 bf16        = 8,388,608
#define OFF_WIH    8388608u         // 2*2048*256 bf16       = 2,097,152
#define OFF_WHH    10485760u        // 2*2048*512 bf16       = 4,194,304
#define OFF_HGLOB  14680064u        // 2*2*64*512 bf16       = 262,144
#define OFF_HS     14942208u        // 16384*1024 bf16       = 33,554,432
#define OFF_EMIS   48496640u        // 16384*6 f32           = 393,216
#define OFF_BAR    48889856u        // 4 groups * 1024 ints  = 16,384

// ---------- kernel 1: prep ----------
__global__ void prep_kernel(const int* __restrict__ sent, const float* __restrict__ embed,
                            const float* __restrict__ Wihf, const float* __restrict__ Whhf,
                            const float* __restrict__ Wihb, const float* __restrict__ Whhb,
                            const float* __restrict__ h0, float* __restrict__ out,
                            ushort_t* __restrict__ x_bf, ushort_t* __restrict__ Wih_bf,
                            ushort_t* __restrict__ Whh_bf, ushort_t* __restrict__ hglob,
                            int* __restrict__ bar) {
    long i = (long)blockIdx.x * 256 + threadIdx.x;
    const long n0 = 2097152, n1 = 1048576, n2 = 4194304, n3 = 65536;
    if (i < n0) {  // Whh cast: [dir][2048][512]
        long d = i >> 20, r = i & 1048575;
        const float* W = d ? Whhb : Whhf;
        Whh_bf[i] = f2bf(W[r]);
        return;
    }
    i -= n0;
    if (i < n1) {  // Wih cast: [dir][2048][256]
        long d = i >> 19, r = i & 524287;
        const float* W = d ? Wihb : Wihf;
        Wih_bf[(d << 19) + r] = f2bf(W[r]);
        return;
    }
    i -= n1;
    if (i < n2) {  // x gather: row = t*B+b
        long row = i >> 8, e = i & 255;
        int tok = sent[row];
        x_bf[i] = f2bf(embed[(size_t)tok * 256 + e]);
        return;
    }
    i -= n2;
    if (i < n3) {  // h0 -> hglob[dir][buf0][b][k]
        long dir = i >> 15, rem = i & 32767;
        hglob[dir * 65536 + rem] = f2bf(h0[i]);
        return;
    }
    i -= n3;
    if (i < 4096) { bar[i] = 0; return; }
    if (i == 4096) { out[0] = 0.f; }
}

// ---------- kernel 2: persistent fused BiLSTM ----------
// 128 WGs: dir(2) x batch-half(2) x gate-slice(32).  256 threads.
__global__ void __launch_bounds__(256, 1) lstm_kernel(
    const ushort_t* __restrict__ x_bf, const ushort_t* __restrict__ Wih_bf,
    const ushort_t* __restrict__ Whh_bf, const float* __restrict__ biasf,
    const float* __restrict__ biasb, const float* __restrict__ c0,
    const int* __restrict__ mask, ushort_t* __restrict__ hglob,
    ushort_t* __restrict__ hs, int* __restrict__ bar) {

    __shared__ __align__(16) ushort_t x_s[32 * 264];
    __shared__ __align__(16) ushort_t h_s[32 * 520];
    __shared__ __align__(16) float gates_s[64 * 33];

    const int tid = threadIdx.x;
    const int wid = blockIdx.x;
    const int dir = wid >> 6;
    const int bh  = (wid >> 5) & 1;
    const int gs  = wid & 31;
    const int j0  = gs * 16;
    const int group = dir * 2 + bh;
    int* flags = &bar[group * 1024];   // 32 peers, 32-int (128B) stride each

    const int lane = tid & 63;
    const int wv = tid >> 6;            // wave = gate type (i,f,g,o)
    const int qo = (lane >> 4) * 8;     // k-chunk offset in fragment
    const int ml = lane & 15;

    // persistent B fragments (W_ih: 8 ksteps, W_hh: 16 ksteps) in VGPRs
    const int grow = wv * 512 + j0 + ml;   // global gate row 0..2047
    short8 bxf[8], bhf[16];
    {
        const ushort_t* wr = Wih_bf + (size_t)dir * G4 * En + (size_t)grow * En + qo;
        #pragma unroll
        for (int ks = 0; ks < 8; ++ks) bxf[ks] = *(const short8*)(wr + ks * 32);
        const ushort_t* wr2 = Whh_bf + (size_t)dir * G4 * Hn + (size_t)grow * Hn + qo;
        #pragma unroll
        for (int ks = 0; ks < 16; ++ks) bhf[ks] = *(const short8*)(wr2 + ks * 32);
    }
    const float bv = (dir ? biasb : biasf)[grow];

    // update-phase mapping (coalesced stores): lane-consecutive j within a batch
    const int jl  = tid & 15;           // h column within slice
    const int bl0 = (tid >> 4) * 2;     // local batch base (2 batches/thread)
    float creg[2];
    #pragma unroll
    for (int r = 0; r < 2; ++r) {
        int bg = bh * 32 + bl0 + r;
        creg[r] = c0[(size_t)dir * Bn * Hn + (size_t)bg * Hn + j0 + jl];
    }

    const ushort_t* xbase = x_bf + (size_t)bh * 32 * En;
    ushort_t* hgbase = hglob + (size_t)dir * 2 * Bn * Hn + (size_t)bh * 32 * Hn;

    // x[t] register prefetch (16KB/WG -> 4 uint4/thread)
    uint4 xreg[4];
    {
        const int t0 = dir ? (Tn - 1) : 0;
        const uint4* g4 = (const uint4*)(xbase + (size_t)t0 * Bn * En);
        #pragma unroll
        for (int k = 0; k < 4; ++k) xreg[k] = g4[tid + k * 256];
    }

    for (int s = 0; s < Tn; ++s) {
        const int t = dir ? (Tn - 1 - s) : s;
        const int cur = s & 1, nxt = cur ^ 1;

        {   // write prefetched x regs to LDS; stage h_cur slice (32KB) from global
            #pragma unroll
            for (int k = 0; k < 4; ++k) {
                int c16 = tid + k * 256;
                int row = c16 >> 5, col = c16 & 31;
                *(uint4*)&x_s[row * 264 + col * 8] = xreg[k];
            }
            const uint4* h4 = (const uint4*)(hgbase + (size_t)cur * Bn * Hn);
            #pragma unroll
            for (int k = 0; k < 8; ++k) {
                int c16 = tid + k * 256;
                int row = c16 >> 6, col = c16 & 63;
                *(uint4*)&h_s[row * 520 + col * 8] = h4[c16];
            }
        }
        __syncthreads();

        // gates = bias + x@Wih^T + h@Whh^T   (M=32 batches, N=16 gates/wave)
        f32x4 acc0, acc1;
        #pragma unroll
        for (int r = 0; r < 4; ++r) { acc0[r] = bv; acc1[r] = bv; }
        {
            const ushort_t* xr0 = &x_s[ml * 264 + qo];
            const ushort_t* xr1 = &x_s[(16 + ml) * 264 + qo];
            #pragma unroll
            for (int ks = 0; ks < 8; ++ks) {
                short8 a0 = *(const short8*)(xr0 + ks * 32);
                short8 a1 = *(const short8*)(xr1 + ks * 32);
                acc0 = __builtin_amdgcn_mfma_f32_16x16x32_bf16(a0, bxf[ks], acc0, 0, 0, 0);
                acc1 = __builtin_amdgcn_mfma_f32_16x16x32_bf16(a1, bxf[ks], acc1, 0, 0, 0);
            }
            const ushort_t* hr0 = &h_s[ml * 520 + qo];
            const ushort_t* hr1 = &h_s[(16 + ml) * 520 + qo];
            #pragma unroll
            for (int ks = 0; ks < 16; ++ks) {
                short8 a0 = *(const short8*)(hr0 + ks * 32);
                short8 a1 = *(const short8*)(hr1 + ks * 32);
                acc0 = __builtin_amdgcn_mfma_f32_16x16x32_bf16(a0, bhf[ks], acc0, 0, 0, 0);
                acc1 = __builtin_amdgcn_mfma_f32_16x16x32_bf16(a1, bhf[ks], acc1, 0, 0, 0);
            }
        }
        {   // C layout: col=lane&15 (gate), row=(lane>>4)*4+reg (batch)
            int nl = wv * 16 + ml;
            int br = (lane >> 4) * 4;
            #pragma unroll
            for (int r = 0; r < 4; ++r) {
                gates_s[nl * 33 + br + r]      = acc0[r];
                gates_s[nl * 33 + 16 + br + r] = acc1[r];
            }
        }
        __syncthreads();

        // cell update: thread -> (jl, bl0..bl0+1); coalesced 32B chunks per batch
        {
            #pragma unroll
            for (int r = 0; r < 2; ++r) {
                int bl = bl0 + r;
                int bg = bh * 32 + bl;
                float iv = gates_s[jl * 33 + bl];
                float fv = gates_s[(16 + jl) * 33 + bl];
                float gv = gates_s[(32 + jl) * 33 + bl];
                float ov = gates_s[(48 + jl) * 33 + bl];
                float cn = sigm(fv) * creg[r] + sigm(iv) * tanh_(gv);
                float hn = sigm(ov) * tanh_(cn);
                int mv = mask[t * Bn + bg];
                float hp = bf2f(h_s[bl * 520 + j0 + jl]);
                float h2, hsv;
                if (mv) { creg[r] = cn; h2 = hn; hsv = hn; }
                else    { h2 = hp; hsv = 0.f; }
                hgbase[(size_t)nxt * Bn * Hn + (size_t)bl * Hn + j0 + jl] = f2bf(h2);
                // nt store: bypass L2 so the release wbl2 has nothing to flush here
                __builtin_nontemporal_store(
                    f2bf(hsv), &hs[((size_t)t * Bn + bg) * 1024 + dir * 512 + j0 + jl]);
            }
        }

        // prefetch next step's x slice BEFORE the barrier (no peer dependency)
        if (s < Tn - 1) {
            const int tn = dir ? (Tn - 2 - s) : (s + 1);
            const uint4* g4 = (const uint4*)(xbase + (size_t)tn * Bn * En);
            #pragma unroll
            for (int k = 0; k < 4; ++k) xreg[k] = g4[tid + k * 256];
        }

        // distributed epoch-flag barrier across the 32 WGs of this group
        __syncthreads();
        if (tid < 32) {
            if (tid == 0) {
                __builtin_amdgcn_fence(__ATOMIC_RELEASE, "agent");
                __hip_atomic_store(&flags[gs * 32], s + 1, __ATOMIC_RELAXED,
                                   __HIP_MEMORY_SCOPE_AGENT);
            }
            int* pf = &flags[tid * 32];
            while (__hip_atomic_load(pf, __ATOMIC_RELAXED, __HIP_MEMORY_SCOPE_AGENT) < s + 1)
                __builtin_amdgcn_s_sleep(2);
            __builtin_amdgcn_fence(__ATOMIC_ACQUIRE, "agent");
        }
        __syncthreads();
    }
}

// ---------- kernel 3: emission projection (wave per row) ----------
__global__ void emis_kernel(const ushort_t* __restrict__ hs, const float* __restrict__ Wout,
                            const float* __restrict__ bout, float* __restrict__ emis) {
    int row = blockIdx.x * 4 + (threadIdx.x >> 6);
    int lane = threadIdx.x & 63;
    const ushort_t* hr = hs + (size_t)row * 1024;
    float acc[6] = {0, 0, 0, 0, 0, 0};
    for (int kk = 0; kk < 16; ++kk) {
        int k = kk * 64 + lane;
        float h = bf2f(hr[k]);
        #pragma unroll
        for (int n = 0; n < Nt; ++n) acc[n] += h * Wout[n * 1024 + k];
    }
    #pragma unroll
    for (int n = 0; n < Nt; ++n) {
        float v = acc[n];
        #pragma unroll
        for (int off = 32; off; off >>= 1) v += __shfl_down(v, off);
        if (lane == 0) emis[row * Nt + n] = v + bout[n];
    }
}

// ---------- kernel 4: CRF LLH (one wave per batch) ----------
__global__ void crf_kernel(const int* __restrict__ tags, const int* __restrict__ mask,
                           const float* __restrict__ emis, const float* __restrict__ trans,
                           const float* __restrict__ startt, const float* __restrict__ endt,
                           float* __restrict__ out) {
    int b = blockIdx.x;
    int lane = threadIdx.x;

    // numerator partials over strided t
    float part = 0.f;
    int mc = 0;
    for (int t = lane; t < Tn; t += 64) {
        int mv = mask[t * Bn + b];
        mc += mv;
        if (t >= 1) {
            int tp = tags[(t - 1) * Bn + b], tc = tags[t * Bn + b];
            part += (trans[tp * Nt + tc] + emis[(t * Bn + b) * Nt + tc]) * (float)mv;
        }
    }
    #pragma unroll
    for (int off = 32; off; off >>= 1) {
        part += __shfl_down(part, off);
        mc += __shfl_down(mc, off);
    }
    float num = 0.f;
    if (lane == 0) {
        int t0g = tags[b];
        num = startt[t0g] + emis[b * Nt + t0g] + part;
        int last = mc - 1;
        num += endt[tags[last * Bn + b]];
    }

    // denominator: forward algorithm, lanes 0..5 hold score[j]
    if (lane < Nt) {
        int j = lane;
        float tr[6];
        #pragma unroll
        for (int i = 0; i < Nt; ++i) tr[i] = trans[i * Nt + j];
        float score = startt[j] + emis[b * Nt + j];
        for (int t = 1; t < Tn; ++t) {
            float e = emis[(t * Bn + b) * Nt + j];
            int mv = mask[t * Bn + b];
            float v[6];
            float mx = -1e30f;
            #pragma unroll
            for (int i = 0; i < Nt; ++i) { v[i] = __shfl(score, i) + tr[i]; mx = fmaxf(mx, v[i]); }
            float sm = 0.f;
            #pragma unroll
            for (int i = 0; i < Nt; ++i) sm += __expf(v[i] - mx);
            float nxtv = mx + __logf(sm) + e;
            score = mv > 0 ? nxtv : score;
        }
        float fvv = score + endt[j];
        float m2 = fvv;
        #pragma unroll
        for (int i = 0; i < Nt; ++i) m2 = fmaxf(m2, __shfl(fvv, i));
        float s2 = 0.f;
        #pragma unroll
        for (int i = 0; i < Nt; ++i) s2 += __expf(__shfl(fvv, i) - m2);
        if (lane == 0) {
            float denom = m2 + __logf(s2);
            atomicAdd(out, num - denom);
        }
    }
}

extern "C" void kernel_launch(void* const* d_in, const int* in_sizes, int n_in,
                              void* d_out, int out_size, void* d_ws, size_t ws_size,
                              hipStream_t stream) {
    (void)in_sizes; (void)n_in; (void)out_size; (void)ws_size;
    const int*   sent  = (const int*)d_in[0];
    const int*   tags  = (const int*)d_in[1];
    const int*   mask  = (const int*)d_in[2];
    const float* h0    = (const float*)d_in[3];
    const float* c0    = (const float*)d_in[4];
    const float* embed = (const float*)d_in[5];
    const float* Wihf  = (const float*)d_in[6];
    const float* Whhf  = (const float*)d_in[7];
    const float* bf_   = (const float*)d_in[8];
    const float* Wihb  = (const float*)d_in[9];
    const float* Whhb  = (const float*)d_in[10];
    const float* bb_   = (const float*)d_in[11];
    const float* Wout  = (const float*)d_in[12];
    const float* bout  = (const float*)d_in[13];
    const float* trans = (const float*)d_in[14];
    const float* stt   = (const float*)d_in[15];
    const float* ent   = (const float*)d_in[16];
    float* out = (float*)d_out;
    char* ws = (char*)d_ws;

    ushort_t* x_bf   = (ushort_t*)(ws + OFF_XBF);
    ushort_t* Wih_bf = (ushort_t*)(ws + OFF_WIH);
    ushort_t* Whh_bf = (ushort_t*)(ws + OFF_WHH);
    ushort_t* hglob  = (ushort_t*)(ws + OFF_HGLOB);
    ushort_t* hs     = (ushort_t*)(ws + OFF_HS);
    float*    emis   = (float*)(ws + OFF_EMIS);
    int*      bar    = (int*)(ws + OFF_BAR);

    prep_kernel<<<28945, 256, 0, stream>>>(sent, embed, Wihf, Whhf, Wihb, Whhb,
                                           h0, out, x_bf, Wih_bf, Whh_bf, hglob, bar);
    lstm_kernel<<<128, 256, 0, stream>>>(x_bf, Wih_bf, Whh_bf, bf_, bb_, c0,
                                         mask, hglob, hs, bar);
    emis_kernel<<<4096, 256, 0, stream>>>(hs, Wout, bout, emis);
    crf_kernel<<<64, 64, 0, stream>>>(tags, mask, emis, trans, stt, ent, out);
}

// Round 4
// 1334.515 us; speedup vs baseline: 3.3060x; 1.3002x over previous
//
#include <hip/hip_runtime.h>

typedef unsigned short ushort_t;
typedef unsigned int uint_t;
typedef __attribute__((ext_vector_type(8))) short short8;
typedef __attribute__((ext_vector_type(4))) float f32x4;
typedef __attribute__((ext_vector_type(4))) uint_t uint4a;

#define Tn 256
#define Bn 64
#define Hn 512
#define En 256
#define G4 2048
#define Nt 6

// ---------- helpers ----------
__device__ inline ushort_t f2bf(float f) {
    uint_t u = __float_as_uint(f);
    uint_t r = u + 0x7FFFu + ((u >> 16) & 1u);
    return (ushort_t)(r >> 16);
}
__device__ inline float bf2f(ushort_t h) { return __uint_as_float(((uint_t)h) << 16); }
__device__ inline float sigm(float x) { return 1.f / (1.f + __expf(-x)); }
__device__ inline float tanh_(float x) { return 2.f / (1.f + __expf(-2.f * x)) - 1.f; }

// device-scope (sc1) memory ops: bypass L1+L2, coherence point = Infinity Cache.
// This is what agent-scope atomics lower to — no wbl2/inv fences needed.
__device__ inline uint4a gload16_sc1(const void* p) {
    uint4a r;
    asm volatile("global_load_dwordx4 %0, %1, off sc1" : "=v"(r) : "v"(p) : "memory");
    return r;
}
__device__ inline void gstore4_sc1(void* p, uint_t v) {
    asm volatile("global_store_dword %0, %1, off sc1" :: "v"(p), "v"(v) : "memory");
}
__device__ inline void vm_drain() { asm volatile("s_waitcnt vmcnt(0)" ::: "memory"); }

// ---------- ws layout (bytes) ----------
#define OFF_XBF    0u               // 16384*256 bf16        = 8,388,608
#define OFF_WIH    8388608u         // 2*2048*256 bf16       = 2,097,152
#define OFF_WHH    10485760u        // 2*2048*512 bf16       = 4,194,304
#define OFF_HGLOB  14680064u        // 2*2*64*512 bf16       = 262,144
#define OFF_HS     14942208u        // 16384*1024 bf16       = 33,554,432
#define OFF_EMIS   48496640u        // 16384*6 f32           = 393,216
#define OFF_BAR    48889856u        // 4 groups * 1024 ints  = 16,384

// ---------- kernel 1: prep ----------
__global__ void prep_kernel(const int* __restrict__ sent, const float* __restrict__ embed,
                            const float* __restrict__ Wihf, const float* __restrict__ Whhf,
                            const float* __restrict__ Wihb, const float* __restrict__ Whhb,
                            const float* __restrict__ h0, float* __restrict__ out,
                            ushort_t* __restrict__ x_bf, ushort_t* __restrict__ Wih_bf,
                            ushort_t* __restrict__ Whh_bf, ushort_t* __restrict__ hglob,
                            int* __restrict__ bar) {
    long i = (long)blockIdx.x * 256 + threadIdx.x;
    const long n0 = 2097152, n1 = 1048576, n2 = 4194304, n3 = 65536;
    if (i < n0) {  // Whh cast: [dir][2048][512]
        long d = i >> 20, r = i & 1048575;
        const float* W = d ? Whhb : Whhf;
        Whh_bf[i] = f2bf(W[r]);
        return;
    }
    i -= n0;
    if (i < n1) {  // Wih cast: [dir][2048][256]
        long d = i >> 19, r = i & 524287;
        const float* W = d ? Wihb : Wihf;
        Wih_bf[(d << 19) + r] = f2bf(W[r]);
        return;
    }
    i -= n1;
    if (i < n2) {  // x gather: row = t*B+b
        long row = i >> 8, e = i & 255;
        int tok = sent[row];
        x_bf[i] = f2bf(embed[(size_t)tok * 256 + e]);
        return;
    }
    i -= n2;
    if (i < n3) {  // h0 -> hglob[dir][buf0][b][k]  (write-through so lstm's sc1 loads see it)
        long dir = i >> 15, rem = i & 32767;
        gstore4_sc1(&hglob[dir * 65536 + (rem & ~1L)],
                    (uint_t)f2bf(h0[(i & ~1L)]) | ((uint_t)f2bf(h0[(i | 1L)]) << 16));
        return;
    }
    i -= n3;
    if (i < 4096) { bar[i] = 0; return; }
    if (i == 4096) { out[0] = 0.f; }
}

// ---------- kernel 2: persistent fused BiLSTM ----------
// 128 WGs: dir(2) x batch-half(2) x gate-slice(32).  256 threads.
__global__ void __launch_bounds__(256, 1) lstm_kernel(
    const ushort_t* __restrict__ x_bf, const ushort_t* __restrict__ Wih_bf,
    const ushort_t* __restrict__ Whh_bf, const float* __restrict__ biasf,
    const float* __restrict__ biasb, const float* __restrict__ c0,
    const int* __restrict__ mask, ushort_t* __restrict__ hglob,
    ushort_t* __restrict__ hs, int* __restrict__ bar) {

    __shared__ __align__(16) ushort_t x_s[2][32 * 264];
    __shared__ __align__(16) ushort_t h_s[32 * 520];
    __shared__ __align__(16) float gates_s[64 * 33];

    const int tid = threadIdx.x;
    const int wid = blockIdx.x;
    const int dir = wid >> 6;
    const int bh  = (wid >> 5) & 1;
    const int gs  = wid & 31;
    const int j0  = gs * 16;
    const int group = dir * 2 + bh;
    int* flags = &bar[group * 1024];   // 32 peers, 32-int (128B) stride each

    const int lane = tid & 63;
    const int wv = tid >> 6;            // wave = gate type (i,f,g,o)
    const int qo = (lane >> 4) * 8;     // k-chunk offset in fragment
    const int ml = lane & 15;

    // persistent B fragments (W_ih: 8 ksteps, W_hh: 16 ksteps) in VGPRs
    const int grow = wv * 512 + j0 + ml;   // global gate row 0..2047
    short8 bxf[8], bhf[16];
    {
        const ushort_t* wr = Wih_bf + (size_t)dir * G4 * En + (size_t)grow * En + qo;
        #pragma unroll
        for (int ks = 0; ks < 8; ++ks) bxf[ks] = *(const short8*)(wr + ks * 32);
        const ushort_t* wr2 = Whh_bf + (size_t)dir * G4 * Hn + (size_t)grow * Hn + qo;
        #pragma unroll
        for (int ks = 0; ks < 16; ++ks) bhf[ks] = *(const short8*)(wr2 + ks * 32);
    }
    const float bv = (dir ? biasb : biasf)[grow];

    // update-phase mapping: thread -> (2 consecutive j, one batch) => one 4B store
    const int jp = (tid & 7) * 2;       // j pair base within slice
    const int bl = tid >> 3;            // local batch 0..31
    const int bg = bh * 32 + bl;
    float creg[2];
    #pragma unroll
    for (int r = 0; r < 2; ++r)
        creg[r] = c0[(size_t)dir * Bn * Hn + (size_t)bg * Hn + j0 + jp + r];

    const ushort_t* xbase = x_bf + (size_t)bh * 32 * En;
    ushort_t* hgbase = hglob + (size_t)dir * 2 * Bn * Hn + (size_t)bh * 32 * Hn;

    // x[t0] prefetch + LDS write (buffer 0)
    uint4 xreg[4];
    {
        const int t0 = dir ? (Tn - 1) : 0;
        const uint4* g4 = (const uint4*)(xbase + (size_t)t0 * Bn * En);
        #pragma unroll
        for (int k = 0; k < 4; ++k) xreg[k] = g4[tid + k * 256];
        #pragma unroll
        for (int k = 0; k < 4; ++k) {
            int c16 = tid + k * 256;
            int row = c16 >> 5, col = c16 & 31;
            *(uint4*)&x_s[0][row * 264 + col * 8] = xreg[k];
        }
    }

    for (int s = 0; s < Tn; ++s) {
        const int t = dir ? (Tn - 1 - s) : s;
        const int cur = s & 1, nxt = cur ^ 1;

        {   // stage h_cur (32KB) via sc1 loads (IF$-coherent), then LDS
            const ushort_t* hp0 = hgbase + (size_t)cur * Bn * Hn;
            uint4a hreg[8];
            #pragma unroll
            for (int k = 0; k < 8; ++k)
                hreg[k] = gload16_sc1(hp0 + (size_t)(tid + k * 256) * 8);
            vm_drain();
            #pragma unroll
            for (int k = 0; k < 8; ++k) {
                int c16 = tid + k * 256;
                int row = c16 >> 6, col = c16 & 63;
                *(uint4a*)&h_s[row * 520 + col * 8] = hreg[k];
            }
        }
        // prefetch next step's x slice (plain cached loads; consumed post-MFMA)
        if (s < Tn - 1) {
            const int tn = dir ? (Tn - 2 - s) : (s + 1);
            const uint4* g4 = (const uint4*)(xbase + (size_t)tn * Bn * En);
            #pragma unroll
            for (int k = 0; k < 4; ++k) xreg[k] = g4[tid + k * 256];
        }
        __syncthreads();

        // gates = bias + x@Wih^T + h@Whh^T   (M=32 batches, N=16 gates/wave)
        f32x4 acc0, acc1;
        #pragma unroll
        for (int r = 0; r < 4; ++r) { acc0[r] = bv; acc1[r] = bv; }
        {
            const ushort_t* xr0 = &x_s[cur][ml * 264 + qo];
            const ushort_t* xr1 = &x_s[cur][(16 + ml) * 264 + qo];
            #pragma unroll
            for (int ks = 0; ks < 8; ++ks) {
                short8 a0 = *(const short8*)(xr0 + ks * 32);
                short8 a1 = *(const short8*)(xr1 + ks * 32);
                acc0 = __builtin_amdgcn_mfma_f32_16x16x32_bf16(a0, bxf[ks], acc0, 0, 0, 0);
                acc1 = __builtin_amdgcn_mfma_f32_16x16x32_bf16(a1, bxf[ks], acc1, 0, 0, 0);
            }
            const ushort_t* hr0 = &h_s[ml * 520 + qo];
            const ushort_t* hr1 = &h_s[(16 + ml) * 520 + qo];
            #pragma unroll
            for (int ks = 0; ks < 16; ++ks) {
                short8 a0 = *(const short8*)(hr0 + ks * 32);
                short8 a1 = *(const short8*)(hr1 + ks * 32);
                acc0 = __builtin_amdgcn_mfma_f32_16x16x32_bf16(a0, bhf[ks], acc0, 0, 0, 0);
                acc1 = __builtin_amdgcn_mfma_f32_16x16x32_bf16(a1, bhf[ks], acc1, 0, 0, 0);
            }
        }
        {   // C layout: col=lane&15 (gate), row=(lane>>4)*4+reg (batch)
            int nl = wv * 16 + ml;
            int br = (lane >> 4) * 4;
            #pragma unroll
            for (int r = 0; r < 4; ++r) {
                gates_s[nl * 33 + br + r]      = acc0[r];
                gates_s[nl * 33 + 16 + br + r] = acc1[r];
            }
        }
        __syncthreads();

        // write next x into the other LDS buffer (xreg loads drained by compiler)
        if (s < Tn - 1) {
            #pragma unroll
            for (int k = 0; k < 4; ++k) {
                int c16 = tid + k * 256;
                int row = c16 >> 5, col = c16 & 31;
                *(uint4*)&x_s[nxt][row * 264 + col * 8] = xreg[k];
            }
        }

        // cell update: thread -> (jp, jp+1) x batch bl; packed 4B stores
        {
            int mv = mask[t * Bn + bg];
            ushort_t hu[2], su[2];
            #pragma unroll
            for (int r = 0; r < 2; ++r) {
                int j = jp + r;
                float iv = gates_s[j * 33 + bl];
                float fv = gates_s[(16 + j) * 33 + bl];
                float gv = gates_s[(32 + j) * 33 + bl];
                float ov = gates_s[(48 + j) * 33 + bl];
                float cn = sigm(fv) * creg[r] + sigm(iv) * tanh_(gv);
                float hn = sigm(ov) * tanh_(cn);
                float hp = bf2f(h_s[bl * 520 + j0 + j]);
                float h2, hsv;
                if (mv) { creg[r] = cn; h2 = hn; hsv = hn; }
                else    { h2 = hp; hsv = 0.f; }
                hu[r] = f2bf(h2);
                su[r] = f2bf(hsv);
            }
            gstore4_sc1(&hgbase[(size_t)nxt * Bn * Hn + (size_t)bl * Hn + j0 + jp],
                        (uint_t)hu[0] | ((uint_t)hu[1] << 16));
            __builtin_nontemporal_store(
                (uint_t)su[0] | ((uint_t)su[1] << 16),
                (uint_t*)&hs[((size_t)t * Bn + bg) * 1024 + dir * 512 + j0 + jp]);
        }
        vm_drain();   // sc1 stores at coherence point => visible before flag

        // distributed epoch-flag barrier (no cache-maintenance fences needed:
        // all cross-WG data moves via sc1 ops, coherent at IF$)
        __syncthreads();
        if (tid < 32) {
            if (tid == 0)
                __hip_atomic_store(&flags[gs * 32], s + 1, __ATOMIC_RELAXED,
                                   __HIP_MEMORY_SCOPE_AGENT);
            int* pf = &flags[tid * 32];
            while (__hip_atomic_load(pf, __ATOMIC_RELAXED, __HIP_MEMORY_SCOPE_AGENT) < s + 1)
                __builtin_amdgcn_s_sleep(1);
        }
        __syncthreads();
    }
}

// ---------- kernel 3: emission projection (wave per row) ----------
__global__ void emis_kernel(const ushort_t* __restrict__ hs, const float* __restrict__ Wout,
                            const float* __restrict__ bout, float* __restrict__ emis) {
    int row = blockIdx.x * 4 + (threadIdx.x >> 6);
    int lane = threadIdx.x & 63;
    const ushort_t* hr = hs + (size_t)row * 1024;
    float acc[6] = {0, 0, 0, 0, 0, 0};
    for (int kk = 0; kk < 16; ++kk) {
        int k = kk * 64 + lane;
        float h = bf2f(hr[k]);
        #pragma unroll
        for (int n = 0; n < Nt; ++n) acc[n] += h * Wout[n * 1024 + k];
    }
    #pragma unroll
    for (int n = 0; n < Nt; ++n) {
        float v = acc[n];
        #pragma unroll
        for (int off = 32; off; off >>= 1) v += __shfl_down(v, off);
        if (lane == 0) emis[row * Nt + n] = v + bout[n];
    }
}

// ---------- kernel 4: CRF LLH (one wave per batch) ----------
__global__ void crf_kernel(const int* __restrict__ tags, const int* __restrict__ mask,
                           const float* __restrict__ emis, const float* __restrict__ trans,
                           const float* __restrict__ startt, const float* __restrict__ endt,
                           float* __restrict__ out) {
    int b = blockIdx.x;
    int lane = threadIdx.x;

    // numerator partials over strided t
    float part = 0.f;
    int mc = 0;
    for (int t = lane; t < Tn; t += 64) {
        int mv = mask[t * Bn + b];
        mc += mv;
        if (t >= 1) {
            int tp = tags[(t - 1) * Bn + b], tc = tags[t * Bn + b];
            part += (trans[tp * Nt + tc] + emis[(t * Bn + b) * Nt + tc]) * (float)mv;
        }
    }
    #pragma unroll
    for (int off = 32; off; off >>= 1) {
        part += __shfl_down(part, off);
        mc += __shfl_down(mc, off);
    }
    float num = 0.f;
    if (lane == 0) {
        int t0g = tags[b];
        num = startt[t0g] + emis[b * Nt + t0g] + part;
        int last = mc - 1;
        num += endt[tags[last * Bn + b]];
    }

    // denominator: forward algorithm, lanes 0..5 hold score[j]
    if (lane < Nt) {
        int j = lane;
        float tr[6];
        #pragma unroll
        for (int i = 0; i < Nt; ++i) tr[i] = trans[i * Nt + j];
        float score = startt[j] + emis[b * Nt + j];
        for (int t = 1; t < Tn; ++t) {
            float e = emis[(t * Bn + b) * Nt + j];
            int mv = mask[t * Bn + b];
            float v[6];
            float mx = -1e30f;
            #pragma unroll
            for (int i = 0; i < Nt; ++i) { v[i] = __shfl(score, i) + tr[i]; mx = fmaxf(mx, v[i]); }
            float sm = 0.f;
            #pragma unroll
            for (int i = 0; i < Nt; ++i) sm += __expf(v[i] - mx);
            float nxtv = mx + __logf(sm) + e;
            score = mv > 0 ? nxtv : score;
        }
        float fvv = score + endt[j];
        float m2 = fvv;
        #pragma unroll
        for (int i = 0; i < Nt; ++i) m2 = fmaxf(m2, __shfl(fvv, i));
        float s2 = 0.f;
        #pragma unroll
        for (int i = 0; i < Nt; ++i) s2 += __expf(__shfl(fvv, i) - m2);
        if (lane == 0) {
            float denom = m2 + __logf(s2);
            atomicAdd(out, num - denom);
        }
    }
}

extern "C" void kernel_launch(void* const* d_in, const int* in_sizes, int n_in,
                              void* d_out, int out_size, void* d_ws, size_t ws_size,
                              hipStream_t stream) {
    (void)in_sizes; (void)n_in; (void)out_size; (void)ws_size;
    const int*   sent  = (const int*)d_in[0];
    const int*   tags  = (const int*)d_in[1];
    const int*   mask  = (const int*)d_in[2];
    const float* h0    = (const float*)d_in[3];
    const float* c0    = (const float*)d_in[4];
    const float* embed = (const float*)d_in[5];
    const float* Wihf  = (const float*)d_in[6];
    const float* Whhf  = (const float*)d_in[7];
    const float* bf_   = (const float*)d_in[8];
    const float* Wihb  = (const float*)d_in[9];
    const float* Whhb  = (const float*)d_in[10];
    const float* bb_   = (const float*)d_in[11];
    const float* Wout  = (const float*)d_in[12];
    const float* bout  = (const float*)d_in[13];
    const float* trans = (const float*)d_in[14];
    const float* stt   = (const float*)d_in[15];
    const float* ent   = (const float*)d_in[16];
    float* out = (float*)d_out;
    char* ws = (char*)d_ws;

    ushort_t* x_bf   = (ushort_t*)(ws + OFF_XBF);
    ushort_t* Wih_bf = (ushort_t*)(ws + OFF_WIH);
    ushort_t* Whh_bf = (ushort_t*)(ws + OFF_WHH);
    ushort_t* hglob  = (ushort_t*)(ws + OFF_HGLOB);
    ushort_t* hs     = (ushort_t*)(ws + OFF_HS);
    float*    emis   = (float*)(ws + OFF_EMIS);
    int*      bar    = (int*)(ws + OFF_BAR);

    prep_kernel<<<28945, 256, 0, stream>>>(sent, embed, Wihf, Whhf, Wihb, Whhb,
                                           h0, out, x_bf, Wih_bf, Whh_bf, hglob, bar);
    lstm_kernel<<<128, 256, 0, stream>>>(x_bf, Wih_bf, Whh_bf, bf_, bb_, c0,
                                         mask, hglob, hs, bar);
    emis_kernel<<<4096, 256, 0, stream>>>(hs, Wout, bout, emis);
    crf_kernel<<<64, 64, 0, stream>>>(tags, mask, emis, trans, stt, ent, out);
}